// Round 8
// baseline (543.103 us; speedup 1.0000x reference)
//
#include <hip/hip_runtime.h>
#include <hip/hip_cooperative_groups.h>

namespace cg = cooperative_groups;

#define D 32
#define GCAP 256
#define FBLK 1024        // fused grid: 1024 blocks x 256 thr = 4 blocks/CU
#define FTHR 256

// ===========================================================================
// Fused cooperative kernel: zero bitmap -> edge atomicOr -> gather+update.
// Agent-scope atomics execute at the coherence point (correct across XCDs);
// __threadfence() around grid.sync() writes back / invalidates L2 so each
// phase sees the previous phase's data.
// ===========================================================================
__global__ __launch_bounds__(FTHR, 4) void gnn_fused(
        const int* __restrict__ src, const int* __restrict__ dst, int E,
        unsigned int* __restrict__ bm, int wpr, int nwords,
        const float* __restrict__ x, float* __restrict__ out,
        const float* __restrict__ W_agg, const float* __restrict__ b_agg,
        const float* __restrict__ W_upd, const float* __restrict__ b_upd) {
    cg::grid_group grid = cg::this_grid();

    __shared__ float sWa[D][D + 1], sWu[D][D + 1], sbias[D];
    __shared__ float sx[16][D], sm[16][D];
    __shared__ int   slist[4][GCAP];

    int t = threadIdx.x;
    int gtid = blockIdx.x * FTHR + t;
    const int T = FBLK * FTHR;

    for (int i = t; i < D * D; i += FTHR) {
        sWa[i >> 5][i & 31] = W_agg[i];
        sWu[i >> 5][i & 31] = W_upd[i];
    }
    if (t < D) sbias[t] = b_agg[t] + b_upd[t];

    // ---- phase 0: zero the 32 MiB bitmap (coalesced uint4 stores) ----
    uint4* bm4 = (uint4*)bm;
    int nq = nwords >> 2;
    uint4 z = make_uint4(0u, 0u, 0u, 0u);
    for (int i = gtid; i < nq; i += T) bm4[i] = z;

    __threadfence();             // release: write back dirty L2 lines
    grid.sync();

    // ---- phase 1: set adjacency bits (idempotent dedup) ----
    for (int e = gtid; e < E; e += T) {
        int s = src[e], d2 = dst[e];
        atomicOr(&bm[(size_t)d2 * wpr + (s >> 5)], 1u << (s & 31));
        atomicOr(&bm[(size_t)s * wpr + (d2 >> 5)], 1u << (d2 & 31));
    }

    __threadfence();
    grid.sync();
    __threadfence();             // acquire: invalidate stale L1/L2 lines

    // ---- phase 2: gather + fused update, 16 nodes/block, 4 nodes/wave ----
    int lane = t & 63, wv = t >> 6, dim = lane & 31, half = lane >> 5;
    int nb0 = blockIdx.x * 16;

    for (int i = t; i < 16 * D; i += FTHR)
        ((float*)sx)[i] = x[(size_t)nb0 * D + i];

    // prefetch all 4 bitmap rows (8 dwordx4 in flight per lane)
    uint4 q[8];
#pragma unroll
    for (int nn = 0; nn < 4; ++nn) {
        const uint4* row4 = (const uint4*)(bm + (size_t)(nb0 + wv * 4 + nn) * wpr);
        q[nn * 2 + 0] = row4[lane];
        q[nn * 2 + 1] = row4[64 + lane];
    }

#pragma unroll
    for (int nn = 0; nn < 4; ++nn) {
        unsigned int w[8] = { q[nn*2].x,   q[nn*2].y,   q[nn*2].z,   q[nn*2].w,
                              q[nn*2+1].x, q[nn*2+1].y, q[nn*2+1].z, q[nn*2+1].w };
        int myc = 0;
#pragma unroll
        for (int k = 0; k < 8; ++k) myc += __popc(w[k]);
        int pre = myc;
#pragma unroll
        for (int off = 1; off < 64; off <<= 1) {
            int v = __shfl_up(pre, off, 64);
            if (lane >= off) pre += v;
        }
        int total = __shfl(pre, 63, 64);
        pre -= myc;

        float acc = 0.f;
        if (total <= GCAP) {
            int p = pre;
#pragma unroll
            for (int k = 0; k < 8; ++k) {
                unsigned int ww = w[k];
                int widx = (k < 4) ? (4 * lane + k) : (256 + 4 * lane + k - 4);
                int base = widx * 32;
                while (ww) {
                    int b = __ffs(ww) - 1;
                    ww &= ww - 1;
                    slist[wv][p++] = base + b;
                }
            }
            __asm__ __volatile__("s_waitcnt lgkmcnt(0)" ::: "memory");

            const int* sl = slist[wv];
            int j = half;
            for (; j + 16 <= total; j += 16) {
                int c0 = sl[j +  0], c1 = sl[j +  2], c2 = sl[j +  4], c3 = sl[j +  6];
                int c4 = sl[j +  8], c5 = sl[j + 10], c6 = sl[j + 12], c7 = sl[j + 14];
                float v0 = x[(size_t)c0 * D + dim];
                float v1 = x[(size_t)c1 * D + dim];
                float v2 = x[(size_t)c2 * D + dim];
                float v3 = x[(size_t)c3 * D + dim];
                float v4 = x[(size_t)c4 * D + dim];
                float v5 = x[(size_t)c5 * D + dim];
                float v6 = x[(size_t)c6 * D + dim];
                float v7 = x[(size_t)c7 * D + dim];
                acc += v0; acc += v1; acc += v2; acc += v3;
                acc += v4; acc += v5; acc += v6; acc += v7;
            }
            for (; j < total; j += 2)
                acc += x[(size_t)sl[j] * D + dim];
        } else {
            // exact high-degree fallback: serial ballot scan
#pragma unroll
            for (int k = 0; k < 8; ++k) {
                unsigned long long m = __ballot(w[k] != 0);
                while (m) {
                    int l = __ffsll(m) - 1;
                    m &= m - 1;
                    unsigned int ww = __shfl(w[k], l, 64);
                    int widx = (k < 4) ? (4 * l + k) : (256 + 4 * l + k - 4);
                    int base = widx * 32;
                    while (ww) {
                        int b = __ffs(ww) - 1;
                        ww &= ww - 1;
                        acc += x[(size_t)(base + b) * D + dim];
                    }
                }
            }
        }
        acc += __shfl_xor(acc, 32, 64);
        if (lane < D) sm[wv * 4 + nn][lane] = acc;
    }
    __syncthreads();

    // ---- fused epilogue: out = b + x*W_upd^T + msg*W_agg^T ----
    for (int o = t; o < 16 * D; o += FTHR) {
        int nl = o >> 5, od = o & 31;
        float r = sbias[od];
#pragma unroll
        for (int k = 0; k < D; ++k)
            r += sx[nl][k] * sWu[od][k] + sm[nl][k] * sWa[od][k];
        out[((size_t)nb0 + nl) * D + od] = r;
    }
}

// ===========================================================================
// Fallback 3-kernel path (round-4 structure, proven 135 us).
// ===========================================================================
__global__ void gnn_edge_bits(const int* __restrict__ src,
                              const int* __restrict__ dst,
                              unsigned int* __restrict__ bm,
                              int E, int wpr) {
    int e = blockIdx.x * blockDim.x + threadIdx.x;
    if (e >= E) return;
    int s = src[e];
    int d = dst[e];
    atomicOr(&bm[(size_t)d * wpr + (s >> 5)], 1u << (s & 31));
    atomicOr(&bm[(size_t)s * wpr + (d >> 5)], 1u << (d & 31));
}

__global__ __launch_bounds__(256) void gnn_gather_update(
        const unsigned int* __restrict__ bm,
        const float* __restrict__ x,
        float* __restrict__ out,
        const float* __restrict__ W_agg,
        const float* __restrict__ b_agg,
        const float* __restrict__ W_upd,
        const float* __restrict__ b_upd,
        int wpr) {
    __shared__ float sWa[D][D + 1];
    __shared__ float sWu[D][D + 1];
    __shared__ float sb[D];
    __shared__ float sx[4][D];
    __shared__ float sm[4][D];
    __shared__ int   slist[4][384];

    int t = threadIdx.x;
    for (int i = t; i < D * D; i += 256) {
        sWa[i >> 5][i & 31] = W_agg[i];
        sWu[i >> 5][i & 31] = W_upd[i];
    }
    if (t < D) sb[t] = b_agg[t] + b_upd[t];

    int lane = t & 63, wv = t >> 6, dim = lane & 31, half = lane >> 5;
    size_t node = (size_t)blockIdx.x * 4 + wv;
    if (lane < D) sx[wv][lane] = x[node * D + lane];

    const unsigned int* row = bm + node * (size_t)wpr;
    unsigned int wb[8];
#pragma unroll
    for (int c = 0; c < 8; ++c) wb[c] = row[c * 64 + lane];

    int myc = 0;
#pragma unroll
    for (int c = 0; c < 8; ++c) myc += __popc(wb[c]);
    int pre = myc;
#pragma unroll
    for (int off = 1; off < 64; off <<= 1) {
        int v = __shfl_up(pre, off, 64);
        if (lane >= off) pre += v;
    }
    int total = __shfl(pre, 63, 64);
    pre -= myc;

    float acc = 0.f;
    if (total <= 384) {
        int p = pre;
#pragma unroll
        for (int c = 0; c < 8; ++c) {
            unsigned int ww = wb[c];
            int base = (c * 64 + lane) * 32;
            while (ww) { int b = __ffs(ww) - 1; ww &= ww - 1; slist[wv][p++] = base + b; }
        }
        __asm__ __volatile__("s_waitcnt lgkmcnt(0)" ::: "memory");
        int j = half;
        for (; j + 8 <= total; j += 8) {
            int c0 = slist[wv][j + 0], c1 = slist[wv][j + 2];
            int c2 = slist[wv][j + 4], c3 = slist[wv][j + 6];
            float v0 = x[(size_t)c0 * D + dim];
            float v1 = x[(size_t)c1 * D + dim];
            float v2 = x[(size_t)c2 * D + dim];
            float v3 = x[(size_t)c3 * D + dim];
            acc += v0; acc += v1; acc += v2; acc += v3;
        }
        for (; j < total; j += 2) acc += x[(size_t)slist[wv][j] * D + dim];
    } else {
        for (int c = 0; c < 8; ++c) {
            unsigned long long m = __ballot(wb[c] != 0);
            while (m) {
                int l = __ffsll(m) - 1; m &= m - 1;
                unsigned int ww = __shfl(wb[c], l, 64);
                int base = (c * 64 + l) * 32;
                while (ww) { int b = __ffs(ww) - 1; ww &= ww - 1;
                             acc += x[(size_t)(base + b) * D + dim]; }
            }
        }
    }
    acc += __shfl_xor(acc, 32, 64);
    if (lane < D) sm[wv][lane] = acc;
    __syncthreads();

    if (t < 128) {
        int ns = t >> 5, o = t & 31;
        float r = sb[o];
#pragma unroll
        for (int k = 0; k < D; ++k)
            r += sx[ns][k] * sWu[o][k] + sm[ns][k] * sWa[o][k];
        out[((size_t)blockIdx.x * 4 + ns) * D + o] = r;
    }
}

// zero-fill kernel (replaces hipMemsetAsync in fallback; identical cost)
__global__ void gnn_zero(uint4* p, int nq) {
    int i = blockIdx.x * blockDim.x + threadIdx.x;
    int T = gridDim.x * blockDim.x;
    uint4 z = make_uint4(0u, 0u, 0u, 0u);
    for (; i < nq; i += T) p[i] = z;
}

// ===========================================================================
// Small-ws fallback: hash-dedup + scattered atomics.
// ===========================================================================
#define HASH_BITS 20
#define HASH_SIZE (1u << HASH_BITS)
#define EMPTY_KEY 0xFFFFFFFFu

__global__ void gnn_edge_scatter(const int* __restrict__ src,
                                 const int* __restrict__ dst,
                                 const float* __restrict__ x,
                                 float* __restrict__ msg,
                                 unsigned int* __restrict__ htab, int E, int N) {
    int e = blockIdx.x * blockDim.x + threadIdx.x;
    if (e >= E) return;
    int s = src[e], d = dst[e];
    int a = s < d ? s : d, b = s < d ? d : s;
    unsigned long long key = (unsigned long long)a * N + b;
    unsigned int k32 = (unsigned int)(key & 0xFFFFFFFEu) | 1u;
    unsigned int h = ((unsigned int)key * 2654435761u) >> (32 - HASH_BITS);
    bool inserted;
    for (;;) {
        unsigned int prev = atomicCAS(&htab[h], EMPTY_KEY, k32);
        if (prev == EMPTY_KEY) { inserted = true; break; }
        if (prev == k32)       { inserted = false; break; }
        h = (h + 1) & (HASH_SIZE - 1);
    }
    if (!inserted) return;
    const float* xs = x + (size_t)s * D;
    const float* xd = x + (size_t)d * D;
    if (s == d) {
        float* m = msg + (size_t)s * D;
#pragma unroll
        for (int i = 0; i < D; ++i) atomicAdd(&m[i], xs[i]);
    } else {
        float* ms = msg + (size_t)s * D;
        float* md = msg + (size_t)d * D;
#pragma unroll
        for (int i = 0; i < D; ++i) {
            atomicAdd(&ms[i], xd[i]);
            atomicAdd(&md[i], xs[i]);
        }
    }
}

__global__ __launch_bounds__(256) void gnn_update(
        const float* __restrict__ x, float* __restrict__ out,
        const float* __restrict__ W_agg, const float* __restrict__ b_agg,
        const float* __restrict__ W_upd, const float* __restrict__ b_upd) {
    __shared__ float sWa[D][D + 1], sWu[D][D + 1], sb[D];
    __shared__ float sx[8][D], sm[8][D];
    int t = threadIdx.x;
    for (int i = t; i < D * D; i += 256) {
        sWa[i >> 5][i & 31] = W_agg[i];
        sWu[i >> 5][i & 31] = W_upd[i];
    }
    if (t < D) sb[t] = b_agg[t] + b_upd[t];
    int g = t >> 5, o = t & 31;
    size_t node = (size_t)blockIdx.x * 8 + g;
    sx[g][o] = x[node * D + o];
    sm[g][o] = out[node * D + o];
    __syncthreads();
    float acc = sb[o];
#pragma unroll
    for (int k = 0; k < D; ++k)
        acc += sx[g][k] * sWu[o][k] + sm[g][k] * sWa[o][k];
    out[node * D + o] = acc;
}

// ===========================================================================

extern "C" void kernel_launch(void* const* d_in, const int* in_sizes, int n_in,
                              void* d_out, int out_size, void* d_ws, size_t ws_size,
                              hipStream_t stream) {
    const float* x     = (const float*)d_in[0];
    const int*   eidx  = (const int*)d_in[1];
    const float* W_agg = (const float*)d_in[2];
    const float* b_agg = (const float*)d_in[3];
    const float* W_upd = (const float*)d_in[4];
    const float* b_upd = (const float*)d_in[5];
    float* out = (float*)d_out;

    int E = in_sizes[1] / 2;
    int N = in_sizes[0] / D;
    const int* src = eidx;
    const int* dst = eidx + E;

    int wpr = N >> 5;
    int nwords = N * wpr;
    size_t bm_bytes = (size_t)nwords * sizeof(unsigned int);   // 32 MiB

    if (N == 16384 && ws_size >= bm_bytes) {
        unsigned int* bm = (unsigned int*)d_ws;
        // try fused cooperative kernel first
        void* args[] = { (void*)&src, (void*)&dst, (void*)&E,
                         (void*)&bm, (void*)&wpr, (void*)&nwords,
                         (void*)&x, (void*)&out,
                         (void*)&W_agg, (void*)&b_agg,
                         (void*)&W_upd, (void*)&b_upd };
        hipError_t err = hipLaunchCooperativeKernel((const void*)gnn_fused,
                                                    dim3(FBLK), dim3(FTHR),
                                                    args, 0, stream);
        if (err == hipSuccess) return;

        // fallback: 3-kernel path (round-4 structure)
        gnn_zero<<<2048, 256, 0, stream>>>((uint4*)bm, nwords >> 2);
        gnn_edge_bits<<<(E + 255) / 256, 256, 0, stream>>>(src, dst, bm, E, wpr);
        gnn_gather_update<<<N / 4, 256, 0, stream>>>(bm, x, out, W_agg, b_agg,
                                                     W_upd, b_upd, wpr);
    } else {
        unsigned int* htab = (unsigned int*)d_ws;
        hipMemsetAsync(out, 0, (size_t)N * D * sizeof(float), stream);
        hipMemsetAsync(htab, 0xFF, (size_t)HASH_SIZE * sizeof(unsigned int), stream);
        gnn_edge_scatter<<<(E + 255) / 256, 256, 0, stream>>>(src, dst, x, out,
                                                              htab, E, N);
        gnn_update<<<N / 8, 256, 0, stream>>>(x, out, W_agg, b_agg, W_upd, b_upd);
    }
}

// Round 9
// 226.111 us; speedup vs baseline: 2.4019x; 2.4019x over previous
//
#include <hip/hip_runtime.h>

#define D 32
#define NPB 64           // nodes per block (fused path)
#define BLK 512          // threads per block (8 waves)
#define SLCAP 160        // per-wave neighbor-list cap (mean degree 64)

// dynamic LDS layout (bytes):
//   bit   [64][512] u32   @0       131072
//   Wa    [32][33]  f32   @131072    4224
//   Wu    [32][33]  f32   @135296    4224
//   bias  [32]      f32   @139520     128
//   sm    [64][32]  f32   @139648    8192
//   sx    [64][32]  f32   @147840    8192
//   slist [8][160]  i32   @156032    5120
#define LDS_BYTES 161152

// ===========================================================================
// K0: pack each edge into one u32 (s:14 | d:14) for a 2 MB L2-resident scan.
// ===========================================================================
__global__ void gnn_pack(const int* __restrict__ src, const int* __restrict__ dst,
                         unsigned int* __restrict__ pe, int E) {
    int i = blockIdx.x * blockDim.x + threadIdx.x;
    if (i < E) pe[i] = ((unsigned int)src[i] << 14) | (unsigned int)dst[i];
}

// ===========================================================================
// K1 (fused): per-block LDS adjacency bitmap for 64 nodes. Scan the full
// packed edge list (L2-hot), LDS atomicOr = idempotent exact dedup; then
// extract + ILP-gather + fused epilogue. No global atomics, no global bitmap.
// ===========================================================================
__global__ __launch_bounds__(BLK, 1) void gnn_fused_lds(
        const unsigned int* __restrict__ pe, int E,
        const float* __restrict__ x, float* __restrict__ out,
        const float* __restrict__ W_agg, const float* __restrict__ b_agg,
        const float* __restrict__ W_upd, const float* __restrict__ b_upd) {
    extern __shared__ char lds[];
    unsigned int* bit = (unsigned int*)lds;                 // [64*512]
    float (*Wa)[D + 1] = (float (*)[D + 1])(lds + 131072);
    float (*Wu)[D + 1] = (float (*)[D + 1])(lds + 135296);
    float* bias        = (float*)(lds + 139520);
    float (*sm)[D]     = (float (*)[D])(lds + 139648);
    float (*sx)[D]     = (float (*)[D])(lds + 147840);
    int*  slall        = (int*)(lds + 156032);

    int t = threadIdx.x;
    int nb0 = blockIdx.x * NPB;
    unsigned int nb0u = (unsigned int)nb0;

    for (int i = t; i < NPB * 512; i += BLK) bit[i] = 0u;
    for (int i = t; i < D * D; i += BLK) {
        Wa[i >> 5][i & 31] = W_agg[i];
        Wu[i >> 5][i & 31] = W_upd[i];
    }
    if (t < D) bias[t] = b_agg[t] + b_upd[t];
    for (int i = t; i < NPB * D; i += BLK)
        ((float*)sx)[i] = x[(size_t)nb0 * D + i];
    __syncthreads();

    // ---- scan packed edges; set bits for this block's 64 nodes ----
#define PROC(u) {                                                         \
        unsigned int s_ = (u) >> 14, d_ = (u) & 16383u;                   \
        unsigned int us = s_ - nb0u;                                      \
        if (us < NPB) atomicOr(&bit[us * 512 + (d_ >> 5)], 1u << (d_ & 31)); \
        unsigned int ud = d_ - nb0u;                                      \
        if (ud < NPB) atomicOr(&bit[ud * 512 + (s_ >> 5)], 1u << (s_ & 31)); }

    int nq4 = E >> 2;
    const uint4* pe4 = (const uint4*)pe;
    for (int i = t; i < nq4; i += BLK) {
        uint4 v = pe4[i];
        PROC(v.x) PROC(v.y) PROC(v.z) PROC(v.w)
    }
    for (int i = (nq4 << 2) + t; i < E; i += BLK) { unsigned int u = pe[i]; PROC(u) }
#undef PROC
    __syncthreads();

    // ---- per-wave: 8 nodes each; extract bits -> slist -> ILP-8 gather ----
    int lane = t & 63, wv = t >> 6, dim = lane & 31, half = lane >> 5;
    int* slist = slall + wv * SLCAP;

    for (int q = 0; q < 8; ++q) {
        int nl = wv * 8 + q;
        const unsigned int* row = bit + nl * 512;
        unsigned int w[8];
#pragma unroll
        for (int c = 0; c < 8; ++c) w[c] = row[c * 64 + lane];

        int myc = 0;
#pragma unroll
        for (int c = 0; c < 8; ++c) myc += __popc(w[c]);
        int pre = myc;
#pragma unroll
        for (int off = 1; off < 64; off <<= 1) {
            int v = __shfl_up(pre, off, 64);
            if (lane >= off) pre += v;
        }
        int total = __shfl(pre, 63, 64);
        pre -= myc;

        float acc = 0.f;
        if (total <= SLCAP) {
            int p = pre;
#pragma unroll
            for (int c = 0; c < 8; ++c) {
                unsigned int ww = w[c];
                int base = (c * 64 + lane) * 32;
                while (ww) { int b = __ffs(ww) - 1; ww &= ww - 1; slist[p++] = base + b; }
            }
            __asm__ __volatile__("s_waitcnt lgkmcnt(0)" ::: "memory");

            int j = half;
            for (; j + 16 <= total; j += 16) {
                int c0 = slist[j +  0], c1 = slist[j +  2], c2 = slist[j +  4], c3 = slist[j +  6];
                int c4 = slist[j +  8], c5 = slist[j + 10], c6 = slist[j + 12], c7 = slist[j + 14];
                float v0 = x[(size_t)c0 * D + dim];
                float v1 = x[(size_t)c1 * D + dim];
                float v2 = x[(size_t)c2 * D + dim];
                float v3 = x[(size_t)c3 * D + dim];
                float v4 = x[(size_t)c4 * D + dim];
                float v5 = x[(size_t)c5 * D + dim];
                float v6 = x[(size_t)c6 * D + dim];
                float v7 = x[(size_t)c7 * D + dim];
                acc += v0; acc += v1; acc += v2; acc += v3;
                acc += v4; acc += v5; acc += v6; acc += v7;
            }
            for (; j < total; j += 2)
                acc += x[(size_t)slist[j] * D + dim];
        } else {
            // exact high-degree fallback: serial ballot scan of the LDS row
            for (int c = 0; c < 8; ++c) {
                unsigned long long m = __ballot(w[c] != 0);
                while (m) {
                    int l = __ffsll(m) - 1; m &= m - 1;
                    unsigned int ww = __shfl(w[c], l, 64);
                    int base = (c * 64 + l) * 32;
                    while (ww) { int b = __ffs(ww) - 1; ww &= ww - 1;
                                 acc += x[(size_t)(base + b) * D + dim]; }
                }
            }
        }
        acc += __shfl_xor(acc, 32, 64);
        if (lane < D) sm[nl][lane] = acc;
    }
    __syncthreads();

    // ---- fused epilogue: out = bias + x*W_upd^T + msg*W_agg^T ----
    for (int o = t; o < NPB * D; o += BLK) {
        int nl = o >> 5, od = o & 31;
        float r = bias[od];
#pragma unroll
        for (int k = 0; k < D; ++k)
            r += sx[nl][k] * Wu[od][k] + sm[nl][k] * Wa[od][k];
        out[((size_t)nb0 + nl) * D + od] = r;
    }
}

// ===========================================================================
// Fallback B: round-4 3-kernel global-bitmap path (proven 135 us).
// ===========================================================================
__global__ void gnn_zero(uint4* p, int nq) {
    int i = blockIdx.x * blockDim.x + threadIdx.x;
    int T = gridDim.x * blockDim.x;
    uint4 z = make_uint4(0u, 0u, 0u, 0u);
    for (; i < nq; i += T) p[i] = z;
}

__global__ void gnn_edge_bits(const int* __restrict__ src,
                              const int* __restrict__ dst,
                              unsigned int* __restrict__ bm, int E, int wpr) {
    int e = blockIdx.x * blockDim.x + threadIdx.x;
    if (e >= E) return;
    int s = src[e], d = dst[e];
    atomicOr(&bm[(size_t)d * wpr + (s >> 5)], 1u << (s & 31));
    atomicOr(&bm[(size_t)s * wpr + (d >> 5)], 1u << (d & 31));
}

__global__ __launch_bounds__(256) void gnn_gather_update4(
        const unsigned int* __restrict__ bm, const float* __restrict__ x,
        float* __restrict__ out,
        const float* __restrict__ W_agg, const float* __restrict__ b_agg,
        const float* __restrict__ W_upd, const float* __restrict__ b_upd, int wpr) {
    __shared__ float sWa[D][D + 1], sWu[D][D + 1], sb[D];
    __shared__ float sx[4][D], sm[4][D];
    __shared__ int   slist[4][384];
    int t = threadIdx.x;
    for (int i = t; i < D * D; i += 256) {
        sWa[i >> 5][i & 31] = W_agg[i];
        sWu[i >> 5][i & 31] = W_upd[i];
    }
    if (t < D) sb[t] = b_agg[t] + b_upd[t];
    int lane = t & 63, wv = t >> 6, dim = lane & 31, half = lane >> 5;
    size_t node = (size_t)blockIdx.x * 4 + wv;
    if (lane < D) sx[wv][lane] = x[node * D + lane];
    const unsigned int* row = bm + node * (size_t)wpr;
    unsigned int wb[8];
#pragma unroll
    for (int c = 0; c < 8; ++c) wb[c] = row[c * 64 + lane];
    int myc = 0;
#pragma unroll
    for (int c = 0; c < 8; ++c) myc += __popc(wb[c]);
    int pre = myc;
#pragma unroll
    for (int off = 1; off < 64; off <<= 1) {
        int v = __shfl_up(pre, off, 64);
        if (lane >= off) pre += v;
    }
    int total = __shfl(pre, 63, 64);
    pre -= myc;
    float acc = 0.f;
    if (total <= 384) {
        int p = pre;
#pragma unroll
        for (int c = 0; c < 8; ++c) {
            unsigned int ww = wb[c];
            int base = (c * 64 + lane) * 32;
            while (ww) { int b = __ffs(ww) - 1; ww &= ww - 1; slist[wv][p++] = base + b; }
        }
        __asm__ __volatile__("s_waitcnt lgkmcnt(0)" ::: "memory");
        int j = half;
        for (; j + 8 <= total; j += 8) {
            int c0 = slist[wv][j + 0], c1 = slist[wv][j + 2];
            int c2 = slist[wv][j + 4], c3 = slist[wv][j + 6];
            float v0 = x[(size_t)c0 * D + dim];
            float v1 = x[(size_t)c1 * D + dim];
            float v2 = x[(size_t)c2 * D + dim];
            float v3 = x[(size_t)c3 * D + dim];
            acc += v0; acc += v1; acc += v2; acc += v3;
        }
        for (; j < total; j += 2) acc += x[(size_t)slist[wv][j] * D + dim];
    } else {
        for (int c = 0; c < 8; ++c) {
            unsigned long long m = __ballot(wb[c] != 0);
            while (m) {
                int l = __ffsll(m) - 1; m &= m - 1;
                unsigned int ww = __shfl(wb[c], l, 64);
                int base = (c * 64 + l) * 32;
                while (ww) { int b = __ffs(ww) - 1; ww &= ww - 1;
                             acc += x[(size_t)(base + b) * D + dim]; }
            }
        }
    }
    acc += __shfl_xor(acc, 32, 64);
    if (lane < D) sm[wv][lane] = acc;
    __syncthreads();
    if (t < 128) {
        int ns = t >> 5, o = t & 31;
        float r = sb[o];
#pragma unroll
        for (int k = 0; k < D; ++k)
            r += sx[ns][k] * sWu[o][k] + sm[ns][k] * sWa[o][k];
        out[((size_t)blockIdx.x * 4 + ns) * D + o] = r;
    }
}

// ===========================================================================
// Fallback C (small ws / odd N): hash-dedup + scattered atomics.
// ===========================================================================
#define HASH_BITS 20
#define HASH_SIZE (1u << HASH_BITS)
#define EMPTY_KEY 0xFFFFFFFFu

__global__ void gnn_edge_scatter(const int* __restrict__ src,
                                 const int* __restrict__ dst,
                                 const float* __restrict__ x,
                                 float* __restrict__ msg,
                                 unsigned int* __restrict__ htab, int E, int N) {
    int e = blockIdx.x * blockDim.x + threadIdx.x;
    if (e >= E) return;
    int s = src[e], d = dst[e];
    int a = s < d ? s : d, b = s < d ? d : s;
    unsigned long long key = (unsigned long long)a * N + b;
    unsigned int k32 = (unsigned int)(key & 0xFFFFFFFEu) | 1u;
    unsigned int h = ((unsigned int)key * 2654435761u) >> (32 - HASH_BITS);
    bool inserted;
    for (;;) {
        unsigned int prev = atomicCAS(&htab[h], EMPTY_KEY, k32);
        if (prev == EMPTY_KEY) { inserted = true; break; }
        if (prev == k32)       { inserted = false; break; }
        h = (h + 1) & (HASH_SIZE - 1);
    }
    if (!inserted) return;
    const float* xs = x + (size_t)s * D;
    const float* xd = x + (size_t)d * D;
    if (s == d) {
        float* m = msg + (size_t)s * D;
#pragma unroll
        for (int i = 0; i < D; ++i) atomicAdd(&m[i], xs[i]);
    } else {
        float* ms = msg + (size_t)s * D;
        float* md = msg + (size_t)d * D;
#pragma unroll
        for (int i = 0; i < D; ++i) {
            atomicAdd(&ms[i], xd[i]);
            atomicAdd(&md[i], xs[i]);
        }
    }
}

__global__ __launch_bounds__(256) void gnn_update(
        const float* __restrict__ x, float* __restrict__ out,
        const float* __restrict__ W_agg, const float* __restrict__ b_agg,
        const float* __restrict__ W_upd, const float* __restrict__ b_upd) {
    __shared__ float sWa[D][D + 1], sWu[D][D + 1], sb[D];
    __shared__ float sx[8][D], sm[8][D];
    int t = threadIdx.x;
    for (int i = t; i < D * D; i += 256) {
        sWa[i >> 5][i & 31] = W_agg[i];
        sWu[i >> 5][i & 31] = W_upd[i];
    }
    if (t < D) sb[t] = b_agg[t] + b_upd[t];
    int g = t >> 5, o = t & 31;
    size_t node = (size_t)blockIdx.x * 8 + g;
    sx[g][o] = x[node * D + o];
    sm[g][o] = out[node * D + o];
    __syncthreads();
    float acc = sb[o];
#pragma unroll
    for (int k = 0; k < D; ++k)
        acc += sx[g][k] * sWu[o][k] + sm[g][k] * sWa[o][k];
    out[node * D + o] = acc;
}

// ===========================================================================

extern "C" void kernel_launch(void* const* d_in, const int* in_sizes, int n_in,
                              void* d_out, int out_size, void* d_ws, size_t ws_size,
                              hipStream_t stream) {
    const float* x     = (const float*)d_in[0];
    const int*   eidx  = (const int*)d_in[1];
    const float* W_agg = (const float*)d_in[2];
    const float* b_agg = (const float*)d_in[3];
    const float* W_upd = (const float*)d_in[4];
    const float* b_upd = (const float*)d_in[5];
    float* out = (float*)d_out;

    int E = in_sizes[1] / 2;
    int N = in_sizes[0] / D;
    const int* src = eidx;
    const int* dst = eidx + E;

    if (N == NPB * 256 && ws_size >= (size_t)E * 4) {
        static hipError_t attr_err = hipFuncSetAttribute(
            (const void*)gnn_fused_lds,
            hipFuncAttributeMaxDynamicSharedMemorySize, LDS_BYTES);
        // (attribute is a per-function property; calling once is sufficient,
        //  and the cached result keeps every launch identical)
        if (attr_err == hipSuccess) {
            unsigned int* pe = (unsigned int*)d_ws;
            gnn_pack<<<(E + 255) / 256, 256, 0, stream>>>(src, dst, pe, E);
            gnn_fused_lds<<<256, BLK, LDS_BYTES, stream>>>(
                pe, E, x, out, W_agg, b_agg, W_upd, b_upd);
            return;
        }
    }

    int wpr = N >> 5;
    size_t bm_bytes = (size_t)N * wpr * sizeof(unsigned int);
    if ((N & 3) == 0 && ws_size >= bm_bytes) {
        unsigned int* bm = (unsigned int*)d_ws;
        gnn_zero<<<2048, 256, 0, stream>>>((uint4*)bm, (N * wpr) >> 2);
        gnn_edge_bits<<<(E + 255) / 256, 256, 0, stream>>>(src, dst, bm, E, wpr);
        gnn_gather_update4<<<N / 4, 256, 0, stream>>>(bm, x, out, W_agg, b_agg,
                                                      W_upd, b_upd, wpr);
    } else {
        unsigned int* htab = (unsigned int*)d_ws;
        hipMemsetAsync(out, 0, (size_t)N * D * sizeof(float), stream);
        hipMemsetAsync(htab, 0xFF, (size_t)HASH_SIZE * sizeof(unsigned int), stream);
        gnn_edge_scatter<<<(E + 255) / 256, 256, 0, stream>>>(src, dst, x, out,
                                                              htab, E, N);
        gnn_update<<<N / 8, 256, 0, stream>>>(x, out, W_agg, b_agg, W_upd, b_upd);
    }
}